// Round 4
// baseline (326.831 us; speedup 1.0000x reference)
//
#include <hip/hip_runtime.h>

// CausalSelfAttention: B=2, T=4096, E=768, H=12, D=64
// fused prep -> QKV GEMM (256x256 8-phase counted-vmcnt, r18) ->
// chunked flash attention (512-kv chunks, kv-step 128, r12-exact, launch_bounds(256,4)) ->
// merge partials -> proj GEMM (128x64 tiles, r17)
// FROZEN LESSONS:
//  - attn body needs ~96 unified regs (64 arch VGPR + 32 AGPR acc). launch_bounds
//    arg 5 or 6 caps below that -> accumulator spill -> 1.3-3.3 GB scratch traffic
//    (r6, r10, r13; VGPR_Count 40/48 signature). ONLY (256,4) works.
//  - r8 (reg-prefetch dbuf), r9 (no-max softmax), r14 (inline-asm cvt_pk) all
//    regressed via codegen-induced scratch/remat traffic. attn dataflow, LDS
//    addressing (r15: padded AP=72/VP=136, NOT swizzle), and perm-pack frozen.
//  - attn noise band across sessions/co-compilation: 126-132us at identical
//    source+counters (r17, rule #19). Don't interpret <5% attn moves.
//  - r17: proj 128x64 re-tile; small gain (old proj was ~22-25us not 35-40:
//    2-3 small blocks DO co-reside per CU, "1.5 blocks/CU" was never serial).
//  - r18 (this round): QKV ported m97-128x128 -> 256x256 8-phase (T3+T4+T5):
//    BK=64, 8 waves, LDS 128KB dbuf, raw s_barrier (NO __syncthreads in the
//    K-loop: its implicit vmcnt(0) drain IS the m97 ceiling), prefetch spread
//    3/3/2 over phases 1-3, single asm vmcnt(0) at phase 4 (loads >=1 phase
//    old -> no stall). Linear LDS, swizzle deferred (r15 lesson: never bundle
//    swizzle with a structure change).

#define SEQT 4096
#define EMB  768
#define NHEAD 12
#define HDIM 64
#define NCHUNK 144   // sum over qt of ceil((qt+1)/4)

typedef __attribute__((ext_vector_type(8))) short bf16x8;
typedef __attribute__((ext_vector_type(4))) float f32x4;
typedef __attribute__((ext_vector_type(16))) float f32x16;

static __device__ __forceinline__ unsigned short f2bf(float f) {
  union { float f; unsigned u; } a; a.f = f;
  unsigned u = a.u;
  u += 0x7FFF + ((u >> 16) & 1);   // RNE
  return (unsigned short)(u >> 16);
}

// pack two f32 -> bf16x2 {lo=a, hi=b} via v_perm_b32 (verified r4)
static __device__ __forceinline__ unsigned pack_bf16(float a, float b) {
  union { float f; unsigned u; } ua, ub; ua.f = a; ub.f = b;
  return __builtin_amdgcn_perm(ub.u + 0x8000u, ua.u + 0x8000u, 0x07060302u);
}

static __device__ __forceinline__ void gload_lds16(const short* g, short* l) {
  __builtin_amdgcn_global_load_lds(
      (const __attribute__((address_space(1))) unsigned*)(const void*)g,
      (__attribute__((address_space(3))) unsigned*)(void*)l, 16, 0, 0);
}

// ---------------- fused prep: cast x -> bf16, transpose W_attn and W_proj ----------------
// grid: [0,6144) cast | [6144,7872) W_attn 72x24 | [7872,8448) W_proj 24x24
__global__ __launch_bounds__(256) void prep_kernel(
    const float* __restrict__ x, short* __restrict__ x_bf,
    const float* __restrict__ W_attn, short* __restrict__ Wt_a,
    const float* __restrict__ W_proj, short* __restrict__ Wt_p) {
  __shared__ float tile[32][33];
  int bid = blockIdx.x;
  int tid = threadIdx.x;
  if (bid < 6144) {
    int i = bid * 256 + tid;     // over 1572864 float4s
    float4 v = ((const float4*)x)[i];
    ushort4 o;
    o.x = f2bf(v.x); o.y = f2bf(v.y); o.z = f2bf(v.z); o.w = f2bf(v.w);
    ((ushort4*)x_bf)[i] = o;
    return;
  }
  const float* in; short* out; int R, C, c0, r0;
  if (bid < 7872) {
    int t = bid - 6144;          // W_attn: [768][2304] -> [2304][768]
    in = W_attn; out = Wt_a; R = 768; C = 2304;
    c0 = (t % 72) * 32; r0 = (t / 72) * 32;
  } else {
    int t = bid - 7872;          // W_proj: [768][768] -> [768][768]
    in = W_proj; out = Wt_p; R = 768; C = 768;
    c0 = (t % 24) * 32; r0 = (t / 24) * 32;
  }
  int tx = tid & 31, ty = tid >> 5;   // 32 x 8
#pragma unroll
  for (int j = 0; j < 32; j += 8)
    tile[ty + j][tx] = in[(size_t)(r0 + ty + j) * C + (c0 + tx)];
  __syncthreads();
#pragma unroll
  for (int j = 0; j < 32; j += 8)
    out[(size_t)(c0 + ty + j) * R + (r0 + tx)] = (short)f2bf(tile[tx][ty + j]);
}

// ---------------- QKV GEMM (r18): 256x256 tile, 8-phase, BK=64, counted vmcnt ---------
// 8 waves (2M x 4N), per-wave 128x64 out, acc[8][4] f32x4, C^T via mfma(B,A).
// LDS: As/Bs double-buffered [2][256][64] bf16 = 128KB total, 1 block/CU.
// Per K-tile: 4 phases x {prefetch-issue, ds_read subtile, s_barrier, setprio,
// 16 MFMA, setprio, s_barrier}. Prefetch of tile t+1 issued 3/3/2 at phases
// 1-3; asm vmcnt(0) at phase 4 (all loads >=1 phase old). Raw s_barrier only.
__global__ __launch_bounds__(512, 2) void gemm_qkv8_kernel(
    const short* __restrict__ A, const short* __restrict__ Bt,
    const float* __restrict__ bias,
    short* __restrict__ Qg, short* __restrict__ Kg, short* __restrict__ Vtg) {
  __shared__ short As[2][256 * 64];
  __shared__ short Bs[2][256 * 64];
  int tid = threadIdx.x;
  int w = tid >> 6, l = tid & 63, quad = l >> 4, lo = l & 15;
  int wm = (w >> 2) * 128, wn = (w & 3) * 64;
  int gm = blockIdx.x, gn = blockIdx.y;
  f32x4 acc[8][4] = {};

  // staging: chunk = w*4+j covers rows chunk*8..chunk*8+7 of the 256-row tile;
  // lane l -> row chunk*8+(l>>3), k-offset (l&7)*8 shorts (16B).
  // LDS dest is linear: base + l*16B (wave-uniform base + lane stride, m104).
  const short* Ag = A  + (size_t)(gm * 256 + (l >> 3)) * 768 + (l & 7) * 8;
  const short* Bg = Bt + (size_t)(gn * 256 + (l >> 3)) * 768 + (l & 7) * 8;
  const int lds_off = w * 2048 + l * 8;   // + j*512 per chunk

  // prologue: stage K-tile 0 into buf 0 (8 loads/thread)
#pragma unroll
  for (int j = 0; j < 4; j++) {
    gload_lds16(Ag + (size_t)(w * 4 + j) * 8 * 768, &As[0][lds_off + j * 512]);
    gload_lds16(Bg + (size_t)(w * 4 + j) * 8 * 768, &Bs[0][lds_off + j * 512]);
  }
  asm volatile("s_waitcnt vmcnt(0)" ::: "memory");
  __builtin_amdgcn_s_barrier();

#pragma unroll 1
  for (int t = 0; t < 12; t++) {
    const int c = t & 1;
    const short* Ac = As[c];
    const short* Bc = Bs[c];
    short* An = (short*)As[c ^ 1];
    short* Bn = (short*)Bs[c ^ 1];
    const bool pf = (t + 1 < 12);
    const int kn = (t + 1) * 64;

    bf16x8 af[4][2], bf[2][2];

    // ---- phase 1: quadrant (m 0-3, n 0-1) ----
    if (pf) {
      gload_lds16(Ag + (size_t)(w * 4 + 0) * 8 * 768 + kn, &An[lds_off + 0 * 512]);
      gload_lds16(Ag + (size_t)(w * 4 + 1) * 8 * 768 + kn, &An[lds_off + 1 * 512]);
      gload_lds16(Ag + (size_t)(w * 4 + 2) * 8 * 768 + kn, &An[lds_off + 2 * 512]);
    }
#pragma unroll
    for (int mt = 0; mt < 4; mt++)
#pragma unroll
      for (int ks = 0; ks < 2; ks++)
        af[mt][ks] = *(const bf16x8*)&Ac[(wm + mt * 16 + lo) * 64 + ks * 32 + quad * 8];
#pragma unroll
    for (int nt = 0; nt < 2; nt++)
#pragma unroll
      for (int ks = 0; ks < 2; ks++)
        bf[nt][ks] = *(const bf16x8*)&Bc[(wn + nt * 16 + lo) * 64 + ks * 32 + quad * 8];
    __builtin_amdgcn_s_barrier();
    __builtin_amdgcn_s_setprio(1);
#pragma unroll
    for (int mt = 0; mt < 4; mt++)
#pragma unroll
      for (int nt = 0; nt < 2; nt++)
#pragma unroll
        for (int ks = 0; ks < 2; ks++)
          acc[mt][nt] = __builtin_amdgcn_mfma_f32_16x16x32_bf16(bf[nt][ks], af[mt][ks], acc[mt][nt], 0, 0, 0);
    __builtin_amdgcn_s_setprio(0);
    __builtin_amdgcn_s_barrier();

    // ---- phase 2: quadrant (m 0-3, n 2-3) ----
    if (pf) {
      gload_lds16(Ag + (size_t)(w * 4 + 3) * 8 * 768 + kn, &An[lds_off + 3 * 512]);
      gload_lds16(Bg + (size_t)(w * 4 + 0) * 8 * 768 + kn, &Bn[lds_off + 0 * 512]);
      gload_lds16(Bg + (size_t)(w * 4 + 1) * 8 * 768 + kn, &Bn[lds_off + 1 * 512]);
    }
#pragma unroll
    for (int nt = 0; nt < 2; nt++)
#pragma unroll
      for (int ks = 0; ks < 2; ks++)
        bf[nt][ks] = *(const bf16x8*)&Bc[(wn + (2 + nt) * 16 + lo) * 64 + ks * 32 + quad * 8];
    __builtin_amdgcn_s_barrier();
    __builtin_amdgcn_s_setprio(1);
#pragma unroll
    for (int mt = 0; mt < 4; mt++)
#pragma unroll
      for (int nt = 0; nt < 2; nt++)
#pragma unroll
        for (int ks = 0; ks < 2; ks++)
          acc[mt][2 + nt] = __builtin_amdgcn_mfma_f32_16x16x32_bf16(bf[nt][ks], af[mt][ks], acc[mt][2 + nt], 0, 0, 0);
    __builtin_amdgcn_s_setprio(0);
    __builtin_amdgcn_s_barrier();

    // ---- phase 3: quadrant (m 4-7, n 0-1) ----
    if (pf) {
      gload_lds16(Bg + (size_t)(w * 4 + 2) * 8 * 768 + kn, &Bn[lds_off + 2 * 512]);
      gload_lds16(Bg + (size_t)(w * 4 + 3) * 8 * 768 + kn, &Bn[lds_off + 3 * 512]);
    }
#pragma unroll
    for (int mt = 0; mt < 4; mt++)
#pragma unroll
      for (int ks = 0; ks < 2; ks++)
        af[mt][ks] = *(const bf16x8*)&Ac[(wm + (4 + mt) * 16 + lo) * 64 + ks * 32 + quad * 8];
#pragma unroll
    for (int nt = 0; nt < 2; nt++)
#pragma unroll
      for (int ks = 0; ks < 2; ks++)
        bf[nt][ks] = *(const bf16x8*)&Bc[(wn + nt * 16 + lo) * 64 + ks * 32 + quad * 8];
    __builtin_amdgcn_s_barrier();
    __builtin_amdgcn_s_setprio(1);
#pragma unroll
    for (int mt = 0; mt < 4; mt++)
#pragma unroll
      for (int nt = 0; nt < 2; nt++)
#pragma unroll
        for (int ks = 0; ks < 2; ks++)
          acc[4 + mt][nt] = __builtin_amdgcn_mfma_f32_16x16x32_bf16(bf[nt][ks], af[mt][ks], acc[4 + mt][nt], 0, 0, 0);
    __builtin_amdgcn_s_setprio(0);
    __builtin_amdgcn_s_barrier();

    // ---- phase 4: quadrant (m 4-7, n 2-3) ----
#pragma unroll
    for (int nt = 0; nt < 2; nt++)
#pragma unroll
      for (int ks = 0; ks < 2; ks++)
        bf[nt][ks] = *(const bf16x8*)&Bc[(wn + (2 + nt) * 16 + lo) * 64 + ks * 32 + quad * 8];
    // all 8 prefetch loads for tile t+1 issued >= 1 phase ago: this wait is
    // counted-by-construction, not a drain-stall.
    asm volatile("s_waitcnt vmcnt(0)" ::: "memory");
    __builtin_amdgcn_s_barrier();
    __builtin_amdgcn_s_setprio(1);
#pragma unroll
    for (int mt = 0; mt < 4; mt++)
#pragma unroll
      for (int nt = 0; nt < 2; nt++)
#pragma unroll
        for (int ks = 0; ks < 2; ks++)
          acc[4 + mt][2 + nt] = __builtin_amdgcn_mfma_f32_16x16x32_bf16(bf[nt][ks], af[mt][ks], acc[4 + mt][2 + nt], 0, 0, 0);
    __builtin_amdgcn_s_setprio(0);
    __builtin_amdgcn_s_barrier();
  }

  // epilogue: C^T regs (reg-dim = n, lane-dim = m), identical packing to r17
#pragma unroll
  for (int nt = 0; nt < 4; nt++) {
    int nb = gn * 256 + wn + nt * 16 + quad * 4;   // 4 consecutive n in regs
    float4 bv = *(const float4*)&bias[nb];
#pragma unroll
    for (int mt = 0; mt < 8; mt++) {
      int m = gm * 256 + wm + mt * 16 + lo;
      int b = m >> 12, tt = m & 4095;
      float v0 = acc[mt][nt][0] + bv.x;
      float v1 = acc[mt][nt][1] + bv.y;
      float v2 = acc[mt][nt][2] + bv.z;
      float v3 = acc[mt][nt][3] + bv.w;
      if (nb < EMB) {
        int h = nb >> 6, d = nb & 63;
        uint2 u; u.x = pack_bf16(v0, v1); u.y = pack_bf16(v2, v3);
        *(uint2*)&Qg[(((size_t)b * NHEAD + h) * SEQT + tt) * HDIM + d] = u;
      } else if (nb < 2 * EMB) {
        int n2 = nb - EMB, h = n2 >> 6, d = n2 & 63;
        uint2 u; u.x = pack_bf16(v0, v1); u.y = pack_bf16(v2, v3);
        *(uint2*)&Kg[(((size_t)b * NHEAD + h) * SEQT + tt) * HDIM + d] = u;
      } else {
        int n2 = nb - 2 * EMB, h = n2 >> 6, d = n2 & 63;
        short* vp = &Vtg[(((size_t)b * NHEAD + h) * HDIM + d) * SEQT + tt];
        vp[0] = (short)f2bf(v0);
        vp[SEQT] = (short)f2bf(v1);
        vp[2 * SEQT] = (short)f2bf(v2);
        vp[3 * SEQT] = (short)f2bf(v3);
      }
    }
  }
}

// ---------------- proj GEMM (r17): 128x64 tile, 4 waves (32 rows each), BK=32 ----------
__global__ __launch_bounds__(256) void gemm_proj_kernel(
    const short* __restrict__ A, const short* __restrict__ Bt,
    const float* __restrict__ bias, float* __restrict__ Out) {
  __shared__ short As[128 * 32];   // 8 KB
  __shared__ short Bs[64 * 32];    // 4 KB
  int tid = threadIdx.x;
  int w = tid >> 6, l = tid & 63, quad = l >> 4, lo = l & 15;
  int gm = blockIdx.x, gn = blockIdx.y;
  f32x4 acc[2][4] = {};
  int c0 = tid, c1 = tid + 256;
  const short* Ag0 = A + (size_t)(gm * 128 + (c0 >> 2)) * EMB + (c0 & 3) * 8;
  const short* Ag1 = A + (size_t)(gm * 128 + (c1 >> 2)) * EMB + (c1 & 3) * 8;
  const short* Bg0 = Bt + (size_t)(gn * 64 + (tid >> 2)) * EMB + (tid & 3) * 8;

  for (int kk = 0; kk < EMB; kk += 32) {
    gload_lds16(Ag0 + kk, &As[c0 * 8]);
    gload_lds16(Ag1 + kk, &As[c1 * 8]);
    gload_lds16(Bg0 + kk, &Bs[tid * 8]);
    __syncthreads();
    bf16x8 af[2], bf[4];
#pragma unroll
    for (int mt = 0; mt < 2; mt++)
      af[mt] = *(const bf16x8*)&As[(w * 32 + mt * 16 + lo) * 32 + quad * 8];
#pragma unroll
    for (int nt = 0; nt < 4; nt++)
      bf[nt] = *(const bf16x8*)&Bs[(nt * 16 + lo) * 32 + quad * 8];
#pragma unroll
    for (int mt = 0; mt < 2; mt++)
#pragma unroll
      for (int nt = 0; nt < 4; nt++)
        acc[mt][nt] = __builtin_amdgcn_mfma_f32_16x16x32_bf16(af[mt], bf[nt], acc[mt][nt], 0, 0, 0);
    __syncthreads();
  }

#pragma unroll
  for (int nt = 0; nt < 4; nt++) {
    int n = gn * 64 + nt * 16 + lo;
    float bias_v = bias[n];
#pragma unroll
    for (int mt = 0; mt < 2; mt++) {
#pragma unroll
      for (int r = 0; r < 4; r++) {
        int m = gm * 128 + w * 32 + mt * 16 + quad * 4 + r;
        Out[(size_t)m * EMB + n] = acc[mt][nt][r] + bias_v;
      }
    }
  }
}

// ---------------- flash attention (r12-exact): chunked kv, kv-step 128 ----------------
// FROZEN. launch_bounds (256,4) only; padded LDS (AP=72/VP=136) only.
#define AP 72     // K rows: 64 d + 8 pad
#define VP 136    // V rows: 128 kv + 8 pad
#define NEG_BIG (-1e9f)
__global__ __launch_bounds__(256, 4) void attn_kernel(
    const short* __restrict__ Qg, const short* __restrict__ Kg,
    const short* __restrict__ Vtg, short* __restrict__ Opart,
    float2* __restrict__ Ml) {
  __shared__ short Ks[128 * AP];   // [kv 128][d 64]
  __shared__ short Vs[64 * VP];    // [d 64][kv 128]
  int tid = threadIdx.x;
  int w = tid >> 6, l = tid & 63;
  int li = l & 31, hi = l >> 5;
  int c = blockIdx.x;
  int bh = blockIdx.y;
  int qt = 31, rem = c;
  while (rem >= ((qt + 4) >> 2)) { rem -= (qt + 4) >> 2; qt--; }
  int p = rem;
  int q0 = qt * 128;
  int cid = bh * NCHUNK + c;
  const short* Qbase = Qg + (size_t)bh * SEQT * HDIM;
  const short* Kbase = Kg + (size_t)bh * SEQT * HDIM;
  const short* Vbase = Vtg + (size_t)bh * HDIM * SEQT;

  int qw = q0 + w * 32;            // wave's 32 q rows
  bf16x8 qf[4];
#pragma unroll
  for (int kk = 0; kk < 4; kk++)
    qf[kk] = *(const bf16x8*)&Qbase[(size_t)(qw + li) * HDIM + kk * 16 + hi * 8];

  f32x16 O[2] = {};
  float m_s = NEG_BIG;
  float l_s = 0.f;

  int kr = tid >> 1, kc = tid & 1;
  int vr = tid >> 2, vc = tid & 3;
  const float SC = 0.18033688011112042f;   // (1/8) * log2(e)
  int s_begin = 4 * p;
  int s_end = min(4 * p + 4, qt + 1);

  for (int s = s_begin; s < s_end; s++) {
    int kv0 = s * 128;
    {
      const short* kg = &Kbase[(size_t)(kv0 + kr) * HDIM + kc * 32];
      uint4 a0 = ((const uint4*)kg)[0];
      uint4 a1 = ((const uint4*)kg)[1];
      uint4 a2 = ((const uint4*)kg)[2];
      uint4 a3 = ((const uint4*)kg)[3];
      short* kd = &Ks[kr * AP + kc * 32];
      ((uint4*)kd)[0] = a0; ((uint4*)kd)[1] = a1;
      ((uint4*)kd)[2] = a2; ((uint4*)kd)[3] = a3;
    }
    {
      const short* vg = &Vbase[(size_t)vr * SEQT + kv0 + vc * 32];
      uint4 b0 = ((const uint4*)vg)[0];
      uint4 b1 = ((const uint4*)vg)[1];
      uint4 b2 = ((const uint4*)vg)[2];
      uint4 b3 = ((const uint4*)vg)[3];
      short* vd = &Vs[vr * VP + vc * 32];
      ((uint4*)vd)[0] = b0; ((uint4*)vd)[1] = b1;
      ((uint4*)vd)[2] = b2; ((uint4*)vd)[3] = b3;
    }
    __syncthreads();

#pragma unroll
    for (int h2 = 0; h2 < 2; h2++) {
      int kvh = kv0 + h2 * 64;
      if (kvh > qw) break;
      bool act1 = (kvh + 32 <= qw);
      bf16x8 ka0[4], ka1[4];
#pragma unroll
      for (int kk = 0; kk < 4; kk++)
        ka0[kk] = *(const bf16x8*)&Ks[(h2 * 64 + li) * AP + kk * 16 + hi * 8];
      if (act1) {
#pragma unroll
        for (int kk = 0; kk < 4; kk++)
          ka1[kk] = *(const bf16x8*)&Ks[(h2 * 64 + 32 + li) * AP + kk * 16 + hi * 8];
      }

      f32x16 st[2];
      {
        f32x16 a = {};
#pragma unroll
        for (int kk = 0; kk < 4; kk++)
          a = __builtin_amdgcn_mfma_f32_32x32x16_bf16(ka0[kk], qf[kk], a, 0, 0, 0);
        st[0] = a;
      }
      if (act1) {
        f32x16 a = {};
#pragma unroll
        for (int kk = 0; kk < 4; kk++)
          a = __builtin_amdgcn_mfma_f32_32x32x16_bf16(ka1[kk], qf[kk], a, 0, 0, 0);
        st[1] = a;
      }

      bool full0 = (kvh < qw);
      float mx = NEG_BIG;
      if (full0) {
#pragma unroll
        for (int r = 0; r < 16; r++) mx = fmaxf(mx, st[0][r]);
      } else {
        int thr = li - 4 * hi;
#pragma unroll
        for (int r = 0; r < 16; r++) {
          const int R = (r & 3) + 8 * (r >> 2);
          st[0][r] = (R <= thr) ? st[0][r] : NEG_BIG;
          mx = fmaxf(mx, st[0][r]);
        }
      }
      if (act1) {
        bool full1 = (kvh + 32 < qw);
        if (full1) {
#pragma unroll
          for (int r = 0; r < 16; r++) mx = fmaxf(mx, st[1][r]);
        } else {
          int thr = li - 4 * hi;
#pragma unroll
          for (int r = 0; r < 16; r++) {
            const int R = (r & 3) + 8 * (r >> 2);
            st[1][r] = (R <= thr) ? st[1][r] : NEG_BIG;
            mx = fmaxf(mx, st[1][r]);
          }
        }
      }
      mx = fmaxf(mx, __shfl_xor(mx, 32));
      float mn = fmaxf(m_s, mx);
      float c1 = SC * mn;
      float al = __builtin_amdgcn_exp2f(fminf(SC * m_s - c1, 0.f));
      m_s = mn;
      float sm = 0.f;
      unsigned pk[2][8];
#pragma unroll
      for (int r2 = 0; r2 < 8; r2++) {
        float pa = __builtin_amdgcn_exp2f(fminf(__builtin_fmaf(st[0][2 * r2],     SC, -c1), 0.f));
        float pb = __builtin_amdgcn_exp2f(fminf(__builtin_fmaf(st[0][2 * r2 + 1], SC, -c1), 0.f));
        sm += pa + pb;
        pk[0][r2] = pack_bf16(pa, pb);
      }
      if (act1) {
#pragma unroll
        for (int r2 = 0; r2 < 8; r2++) {
          float pa = __builtin_amdgcn_exp2f(fminf(__builtin_fmaf(st[1][2 * r2],     SC, -c1), 0.f));
          float pb = __builtin_amdgcn_exp2f(fminf(__builtin_fmaf(st[1][2 * r2 + 1], SC, -c1), 0.f));
          sm += pa + pb;
          pk[1][r2] = pack_bf16(pa, pb);
        }
      }
      sm += __shfl_xor(sm, 32);
      l_s = l_s * al + sm;
#pragma unroll
      for (int dt = 0; dt < 2; dt++)
#pragma unroll
        for (int r = 0; r < 16; r++) O[dt][r] *= al;

#pragma unroll
      for (int g = 0; g < 4; g++) {
        int t = g >> 1, k2 = g & 1;
        if (t == 1 && !act1) continue;
        unsigned own_a = hi ? pk[t][k2 * 4 + 2] : pk[t][k2 * 4 + 0];
        unsigned own_b = hi ? pk[t][k2 * 4 + 3] : pk[t][k2 * 4 + 1];
        unsigned snd_a = hi ? pk[t][k2 * 4 + 0] : pk[t][k2 * 4 + 2];
        unsigned snd_b = hi ? pk[t][k2 * 4 + 1] : pk[t][k2 * 4 + 3];
        unsigned rcv_a = (unsigned)__shfl_xor((int)snd_a, 32);
        unsigned rcv_b = (unsigned)__shfl_xor((int)snd_b, 32);
        union { unsigned u[4]; bf16x8 v; } pf;
        pf.u[0] = hi ? rcv_a : own_a;
        pf.u[1] = hi ? rcv_b : own_b;
        pf.u[2] = hi ? own_a : rcv_a;
        pf.u[3] = hi ? own_b : rcv_b;
        bf16x8 va0 = *(const bf16x8*)&Vs[li * VP + h2 * 64 + g * 16 + hi * 8];
        bf16x8 va1 = *(const bf16x8*)&Vs[(32 + li) * VP + h2 * 64 + g * 16 + hi * 8];
        O[0] = __builtin_amdgcn_mfma_f32_32x32x16_bf16(va0, pf.v, O[0], 0, 0, 0);
        O[1] = __builtin_amdgcn_mfma_f32_32x32x16_bf16(va1, pf.v, O[1], 0, 0, 0);
      }
    }
    __syncthreads();
  }

  int lq = w * 32 + li;
  short* op = &Opart[((size_t)cid * 128 + lq) * 64];
#pragma unroll
  for (int dt = 0; dt < 2; dt++) {
#pragma unroll
    for (int rg = 0; rg < 4; rg++) {
      uint2 u2;
      u2.x = pack_bf16(O[dt][rg * 4 + 0], O[dt][rg * 4 + 1]);
      u2.y = pack_bf16(O[dt][rg * 4 + 2], O[dt][rg * 4 + 3]);
      *(uint2*)(op + dt * 32 + rg * 8 + hi * 4) = u2;
    }
  }
  if (hi == 0) {
    float2 ml; ml.x = m_s; ml.y = l_s;
    Ml[(size_t)cid * 128 + lq] = ml;
  }
}

// ---------------- merge partials ----------------
__global__ __launch_bounds__(256) void merge_kernel(
    const short* __restrict__ Opart, const float2* __restrict__ Ml,
    short* __restrict__ Y) {
  int qt = blockIdx.x, bh = blockIdx.y;
  int n = (qt + 4) >> 2;
  int cbase = 0;
  for (int j = qt + 1; j < 32; j++) cbase += (j + 4) >> 2;
  int tid = threadIdx.x;
  int lq = tid >> 1, half = tid & 1;
  int b = bh / NHEAD, h = bh % NHEAD;
  int q = qt * 128 + lq;
  const float SC = 0.18033688011112042f;

  float m_i[8], l_i[8];
  float mstar = NEG_BIG;
#pragma unroll 4
  for (int i = 0; i < n; i++) {
    float2 ml = Ml[((size_t)bh * NCHUNK + cbase + i) * 128 + lq];
    m_i[i] = ml.x; l_i[i] = ml.y;
    mstar = fmaxf(mstar, ml.x);
  }
  float lstar = 0.f;
  float wgt[8];
#pragma unroll 4
  for (int i = 0; i < n; i++) {
    wgt[i] = __builtin_amdgcn_exp2f(fminf(SC * (m_i[i] - mstar), 0.f));
    lstar += l_i[i] * wgt[i];
  }

  float acc[32] = {};
#pragma unroll 4
  for (int i = 0; i < n; i++) {
    const short* op = &Opart[(((size_t)bh * NCHUNK + cbase + i) * 128 + lq) * 64 + half * 32];
    float wi = wgt[i];
#pragma unroll
    for (int v = 0; v < 4; v++) {
      uint4 u = ((const uint4*)op)[v];
      unsigned uu[4] = {u.x, u.y, u.z, u.w};
#pragma unroll
      for (int j = 0; j < 4; j++) {
        union { unsigned u; float f; } lo2, hi2;
        lo2.u = uu[j] << 16;
        hi2.u = uu[j] & 0xFFFF0000u;
        acc[v * 8 + j * 2]     = __builtin_fmaf(lo2.f, wi, acc[v * 8 + j * 2]);
        acc[v * 8 + j * 2 + 1] = __builtin_fmaf(hi2.f, wi, acc[v * 8 + j * 2 + 1]);
      }
    }
  }
  float rl = 1.f / lstar;
  short* yp = &Y[((size_t)b * SEQT + q) * EMB + h * 64 + half * 32];
#pragma unroll
  for (int v = 0; v < 4; v++) {
    uint2 u2;
    u2.x = pack_bf16(acc[v * 8 + 0] * rl, acc[v * 8 + 1] * rl);
    u2.y = pack_bf16(acc[v * 8 + 2] * rl, acc[v * 8 + 3] * rl);
    uint2 u3;
    u3.x = pack_bf16(acc[v * 8 + 4] * rl, acc[v * 8 + 5] * rl);
    u3.y = pack_bf16(acc[v * 8 + 6] * rl, acc[v * 8 + 7] * rl);
    *(uint2*)(yp + v * 8) = u2;
    *(uint2*)(yp + v * 8 + 4) = u3;
  }
}

extern "C" void kernel_launch(void* const* d_in, const int* in_sizes, int n_in,
                              void* d_out, int out_size, void* d_ws, size_t ws_size,
                              hipStream_t stream) {
  const float* x      = (const float*)d_in[0];   // [2,4096,768]
  const float* W_attn = (const float*)d_in[1];   // [768,2304]
  const float* b_attn = (const float*)d_in[2];   // [2304]
  const float* W_proj = (const float*)d_in[3];   // [768,768]
  const float* b_proj = (const float*)d_in[4];   // [768]
  float* out = (float*)d_out;                    // [2,4096,768] fp32

  char* ws = (char*)d_ws;
  short* x_bf  = (short*)(ws + 0);           // 8192x768 bf16
  short* Wt_a  = (short*)(ws + 12582912);    // 2304x768 bf16
  short* Wt_p  = (short*)(ws + 16121856);    // 768x768  bf16
  short* Qg    = (short*)(ws + 17301504);    // [2,12,4096,64]
  short* Kg    = (short*)(ws + 29884416);    // [2,12,4096,64]
  short* Vtg   = (short*)(ws + 42467328);    // [2,12,64,4096]
  short* Ybf   = (short*)(ws + 55050240);    // 8192x768 bf16
  short* Opart = (short*)(ws + 67633152);    // 3456 x 128 x 64 bf16 = 56,623,104 B
  float2* Ml   = (float2*)(ws + 124256256);  // 3456 x 128 float2 = 3,538,944 B
  // total 127,795,200 B

  prep_kernel<<<8448, 256, 0, stream>>>(x, x_bf, W_attn, Wt_a, W_proj, Wt_p);

  gemm_qkv8_kernel<<<dim3(32, 9), 512, 0, stream>>>(x_bf, Wt_a, b_attn,
                                                    Qg, Kg, Vtg);
  attn_kernel<<<dim3(NCHUNK, 24), 256, 0, stream>>>(Qg, Kg, Vtg, Opart, Ml);
  merge_kernel<<<dim3(32, 24), 256, 0, stream>>>(Opart, Ml, Ybf);
  gemm_proj_kernel<<<dim3(64, 12), 256, 0, stream>>>(Ybf, Wt_p, b_proj, out);
}

// Round 5
// 278.253 us; speedup vs baseline: 1.1746x; 1.1746x over previous
//
#include <hip/hip_runtime.h>

// CausalSelfAttention: B=2, T=4096, E=768, H=12, D=64
// fused prep -> QKV GEMM (m97-style, C^T epilogue) ->
// chunked flash attention (512-kv chunks, kv-step 128, r12-exact, launch_bounds(256,4)) ->
// merge partials -> proj GEMM (128x64 tiles, r17)
// FROZEN LESSONS:
//  - attn body needs ~96 unified regs (64 arch VGPR + 32 AGPR acc). launch_bounds
//    arg 5 or 6 caps below that -> accumulator spill -> 1.3-3.3 GB scratch traffic
//    (r6, r10, r13; VGPR_Count 40/48 signature). ONLY (256,4) works.
//  - r8 (reg-prefetch dbuf), r9 (no-max softmax), r14 (inline-asm cvt_pk) all
//    regressed via codegen-induced scratch/remat traffic. attn dataflow, LDS
//    addressing (r15: padded AP=72/VP=136, NOT swizzle), and perm-pack frozen.
//  - attn noise band across sessions/co-compilation: 124-132us at identical
//    source+counters (r17, rule #19). Don't interpret <5% attn moves.
//  - r15 FAILED: XOR-swizzle attn LDS -> conflicts 5x, WRITE_SIZE 3x, reverted.
//  - r17: proj 128x64 re-tile (64x12 grid, 3 blocks/CU); small gain.
//  - r18 FAILED (reverted): QKV 256x256 8-phase (T3+T4+T5) port. QKV ~75 ->
//    ~120us despite correct math. Root causes, all structural: (a) BK=64
//    linear LDS has 128B row stride = one bank cycle -> ds_read_b128 column
//    reads land in half the banks (the conflict m201's st_16x32 swizzle
//    exists to fix; I deferred the swizzle but kept its cost); (b) grid
//    32x9=288 blocks at 1 block/CU (128KB LDS) = 2 dispatch rounds, 2nd
//    round 32/256 CUs -> 56% util, IRREDUCIBLE at 256^2 for N=2304. Even a
//    perfect port ~= baseline. 256^2-8phase is geometrically disqualified
//    for this shape; 128^2-8phase is a documented null (m232). QKV stays
//    m97-128^2 (4.5 blocks/CU, benign 64B-row bank pattern, backfilled
//    tail); its pipelining ceiling is documented (m99-m141 all null).

#define SEQT 4096
#define EMB  768
#define NHEAD 12
#define HDIM 64
#define NCHUNK 144   // sum over qt of ceil((qt+1)/4)

typedef __attribute__((ext_vector_type(8))) short bf16x8;
typedef __attribute__((ext_vector_type(4))) float f32x4;
typedef __attribute__((ext_vector_type(16))) float f32x16;

static __device__ __forceinline__ unsigned short f2bf(float f) {
  union { float f; unsigned u; } a; a.f = f;
  unsigned u = a.u;
  u += 0x7FFF + ((u >> 16) & 1);   // RNE
  return (unsigned short)(u >> 16);
}

// pack two f32 -> bf16x2 {lo=a, hi=b} via v_perm_b32 (verified r4; r14's inline-asm
// v_cvt_pk_bf16_f32 variant broke the allocator -> 3x WRITE_SIZE, +52% attn time)
static __device__ __forceinline__ unsigned pack_bf16(float a, float b) {
  union { float f; unsigned u; } ua, ub; ua.f = a; ub.f = b;
  return __builtin_amdgcn_perm(ub.u + 0x8000u, ua.u + 0x8000u, 0x07060302u);
}

static __device__ __forceinline__ void gload_lds16(const short* g, short* l) {
  __builtin_amdgcn_global_load_lds(
      (const __attribute__((address_space(1))) unsigned*)(const void*)g,
      (__attribute__((address_space(3))) unsigned*)(void*)l, 16, 0, 0);
}

// ---------------- fused prep: cast x -> bf16, transpose W_attn and W_proj ----------------
// grid: [0,6144) cast | [6144,7872) W_attn 72x24 | [7872,8448) W_proj 24x24
__global__ __launch_bounds__(256) void prep_kernel(
    const float* __restrict__ x, short* __restrict__ x_bf,
    const float* __restrict__ W_attn, short* __restrict__ Wt_a,
    const float* __restrict__ W_proj, short* __restrict__ Wt_p) {
  __shared__ float tile[32][33];
  int bid = blockIdx.x;
  int tid = threadIdx.x;
  if (bid < 6144) {
    int i = bid * 256 + tid;     // over 1572864 float4s
    float4 v = ((const float4*)x)[i];
    ushort4 o;
    o.x = f2bf(v.x); o.y = f2bf(v.y); o.z = f2bf(v.z); o.w = f2bf(v.w);
    ((ushort4*)x_bf)[i] = o;
    return;
  }
  const float* in; short* out; int R, C, c0, r0;
  if (bid < 7872) {
    int t = bid - 6144;          // W_attn: [768][2304] -> [2304][768]
    in = W_attn; out = Wt_a; R = 768; C = 2304;
    c0 = (t % 72) * 32; r0 = (t / 72) * 32;
  } else {
    int t = bid - 7872;          // W_proj: [768][768] -> [768][768]
    in = W_proj; out = Wt_p; R = 768; C = 768;
    c0 = (t % 24) * 32; r0 = (t / 24) * 32;
  }
  int tx = tid & 31, ty = tid >> 5;   // 32 x 8
#pragma unroll
  for (int j = 0; j < 32; j += 8)
    tile[ty + j][tx] = in[(size_t)(r0 + ty + j) * C + (c0 + tx)];
  __syncthreads();
#pragma unroll
  for (int j = 0; j < 32; j += 8)
    out[(size_t)(c0 + ty + j) * R + (r0 + tx)] = (short)f2bf(tile[tx][ty + j]);
}

// ---------------- QKV GEMM (m97-style): 128x128 tile, 4 waves, BK=32, global_load_lds
// C^T in regs (mfma(B,A)) -> packed Q/K stores + Vt scatter
__global__ __launch_bounds__(256) void gemm_qkv_kernel(
    const short* __restrict__ A, const short* __restrict__ Bt,
    const float* __restrict__ bias, int K,
    short* __restrict__ Qg, short* __restrict__ Kg, short* __restrict__ Vtg) {
  __shared__ short As[128 * 32];
  __shared__ short Bs[128 * 32];
  int tid = threadIdx.x;
  int w = tid >> 6, l = tid & 63, quad = l >> 4, lo = l & 15;
  int wm = (w >> 1) * 64, wn = (w & 1) * 64;
  int gm = blockIdx.x, gn = blockIdx.y;
  f32x4 acc[4][4] = {};
  int c0 = tid, c1 = tid + 256;   // 16B chunks: row=c>>2, k-sub=(c&3)*8
  const short* Ag0 = A + (size_t)(gm * 128 + (c0 >> 2)) * K + (c0 & 3) * 8;
  const short* Ag1 = A + (size_t)(gm * 128 + (c1 >> 2)) * K + (c1 & 3) * 8;
  const short* Bg0 = Bt + (size_t)(gn * 128 + (c0 >> 2)) * K + (c0 & 3) * 8;
  const short* Bg1 = Bt + (size_t)(gn * 128 + (c1 >> 2)) * K + (c1 & 3) * 8;

  for (int kk = 0; kk < K; kk += 32) {
    gload_lds16(Ag0 + kk, &As[c0 * 8]);
    gload_lds16(Ag1 + kk, &As[c1 * 8]);
    gload_lds16(Bg0 + kk, &Bs[c0 * 8]);
    gload_lds16(Bg1 + kk, &Bs[c1 * 8]);
    __syncthreads();
    bf16x8 af[4], bf[4];
#pragma unroll
    for (int mt = 0; mt < 4; mt++)
      af[mt] = *(const bf16x8*)&As[(wm + mt * 16 + lo) * 32 + quad * 8];
#pragma unroll
    for (int nt = 0; nt < 4; nt++)
      bf[nt] = *(const bf16x8*)&Bs[(wn + nt * 16 + lo) * 32 + quad * 8];
#pragma unroll
    for (int mt = 0; mt < 4; mt++)
#pragma unroll
      for (int nt = 0; nt < 4; nt++)   // C^T: reg-dim = n, lane-dim = m
        acc[mt][nt] = __builtin_amdgcn_mfma_f32_16x16x32_bf16(bf[nt], af[mt], acc[mt][nt], 0, 0, 0);
    __syncthreads();
  }

#pragma unroll
  for (int nt = 0; nt < 4; nt++) {
    int nb = gn * 128 + wn + nt * 16 + quad * 4;   // 4 consecutive n in regs
    float4 bv = *(const float4*)&bias[nb];
#pragma unroll
    for (int mt = 0; mt < 4; mt++) {
      int m = gm * 128 + wm + mt * 16 + lo;
      int b = m >> 12, t = m & 4095;
      float v0 = acc[mt][nt][0] + bv.x;
      float v1 = acc[mt][nt][1] + bv.y;
      float v2 = acc[mt][nt][2] + bv.z;
      float v3 = acc[mt][nt][3] + bv.w;
      if (nb < EMB) {
        int h = nb >> 6, d = nb & 63;
        uint2 u; u.x = pack_bf16(v0, v1); u.y = pack_bf16(v2, v3);
        *(uint2*)&Qg[(((size_t)b * NHEAD + h) * SEQT + t) * HDIM + d] = u;
      } else if (nb < 2 * EMB) {
        int n2 = nb - EMB, h = n2 >> 6, d = n2 & 63;
        uint2 u; u.x = pack_bf16(v0, v1); u.y = pack_bf16(v2, v3);
        *(uint2*)&Kg[(((size_t)b * NHEAD + h) * SEQT + t) * HDIM + d] = u;
      } else {
        int n2 = nb - 2 * EMB, h = n2 >> 6, d = n2 & 63;
        short* vp = &Vtg[(((size_t)b * NHEAD + h) * HDIM + d) * SEQT + t];
        vp[0] = (short)f2bf(v0);
        vp[SEQT] = (short)f2bf(v1);
        vp[2 * SEQT] = (short)f2bf(v2);
        vp[3 * SEQT] = (short)f2bf(v3);
      }
    }
  }
}

// ---------------- proj GEMM (r17): 128x64 tile, 4 waves (32 rows each), BK=32 ----------
// Grid 64x12 = 768 blocks = 3 blocks/CU. Same m97 K-loop skeleton.
__global__ __launch_bounds__(256) void gemm_proj_kernel(
    const short* __restrict__ A, const short* __restrict__ Bt,
    const float* __restrict__ bias, float* __restrict__ Out) {
  __shared__ short As[128 * 32];   // 8 KB
  __shared__ short Bs[64 * 32];    // 4 KB
  int tid = threadIdx.x;
  int w = tid >> 6, l = tid & 63, quad = l >> 4, lo = l & 15;
  int gm = blockIdx.x, gn = blockIdx.y;
  f32x4 acc[2][4] = {};
  int c0 = tid, c1 = tid + 256;
  const short* Ag0 = A + (size_t)(gm * 128 + (c0 >> 2)) * EMB + (c0 & 3) * 8;
  const short* Ag1 = A + (size_t)(gm * 128 + (c1 >> 2)) * EMB + (c1 & 3) * 8;
  const short* Bg0 = Bt + (size_t)(gn * 64 + (tid >> 2)) * EMB + (tid & 3) * 8;

  for (int kk = 0; kk < EMB; kk += 32) {
    gload_lds16(Ag0 + kk, &As[c0 * 8]);
    gload_lds16(Ag1 + kk, &As[c1 * 8]);
    gload_lds16(Bg0 + kk, &Bs[tid * 8]);
    __syncthreads();
    bf16x8 af[2], bf[4];
#pragma unroll
    for (int mt = 0; mt < 2; mt++)
      af[mt] = *(const bf16x8*)&As[(w * 32 + mt * 16 + lo) * 32 + quad * 8];
#pragma unroll
    for (int nt = 0; nt < 4; nt++)
      bf[nt] = *(const bf16x8*)&Bs[(nt * 16 + lo) * 32 + quad * 8];
#pragma unroll
    for (int mt = 0; mt < 2; mt++)
#pragma unroll
      for (int nt = 0; nt < 4; nt++)
        acc[mt][nt] = __builtin_amdgcn_mfma_f32_16x16x32_bf16(af[mt], bf[nt], acc[mt][nt], 0, 0, 0);
    __syncthreads();
  }

#pragma unroll
  for (int nt = 0; nt < 4; nt++) {
    int n = gn * 64 + nt * 16 + lo;
    float bias_v = bias[n];
#pragma unroll
    for (int mt = 0; mt < 2; mt++) {
#pragma unroll
      for (int r = 0; r < 4; r++) {
        int m = gm * 128 + w * 32 + mt * 16 + quad * 4 + r;
        Out[(size_t)m * EMB + n] = acc[mt][nt][r] + bias_v;
      }
    }
  }
}

// ---------------- flash attention (r12-exact): chunked kv, kv-step 128 ----------------
// FROZEN. launch_bounds (256,4) only; padded LDS (AP=72/VP=136) only.
#define AP 72     // K rows: 64 d + 8 pad
#define VP 136    // V rows: 128 kv + 8 pad
#define NEG_BIG (-1e9f)
__global__ __launch_bounds__(256, 4) void attn_kernel(
    const short* __restrict__ Qg, const short* __restrict__ Kg,
    const short* __restrict__ Vtg, short* __restrict__ Opart,
    float2* __restrict__ Ml) {
  __shared__ short Ks[128 * AP];   // [kv 128][d 64]
  __shared__ short Vs[64 * VP];    // [d 64][kv 128]
  int tid = threadIdx.x;
  int w = tid >> 6, l = tid & 63;
  int li = l & 31, hi = l >> 5;
  int c = blockIdx.x;
  int bh = blockIdx.y;
  int qt = 31, rem = c;
  while (rem >= ((qt + 4) >> 2)) { rem -= (qt + 4) >> 2; qt--; }
  int p = rem;
  int q0 = qt * 128;
  int cid = bh * NCHUNK + c;
  const short* Qbase = Qg + (size_t)bh * SEQT * HDIM;
  const short* Kbase = Kg + (size_t)bh * SEQT * HDIM;
  const short* Vbase = Vtg + (size_t)bh * HDIM * SEQT;

  int qw = q0 + w * 32;            // wave's 32 q rows
  bf16x8 qf[4];
#pragma unroll
  for (int kk = 0; kk < 4; kk++)
    qf[kk] = *(const bf16x8*)&Qbase[(size_t)(qw + li) * HDIM + kk * 16 + hi * 8];

  f32x16 O[2] = {};
  float m_s = NEG_BIG;
  float l_s = 0.f;

  int kr = tid >> 1, kc = tid & 1;
  int vr = tid >> 2, vc = tid & 3;
  const float SC = 0.18033688011112042f;   // (1/8) * log2(e)
  int s_begin = 4 * p;
  int s_end = min(4 * p + 4, qt + 1);

  for (int s = s_begin; s < s_end; s++) {
    int kv0 = s * 128;
    {
      const short* kg = &Kbase[(size_t)(kv0 + kr) * HDIM + kc * 32];
      uint4 a0 = ((const uint4*)kg)[0];
      uint4 a1 = ((const uint4*)kg)[1];
      uint4 a2 = ((const uint4*)kg)[2];
      uint4 a3 = ((const uint4*)kg)[3];
      short* kd = &Ks[kr * AP + kc * 32];
      ((uint4*)kd)[0] = a0; ((uint4*)kd)[1] = a1;
      ((uint4*)kd)[2] = a2; ((uint4*)kd)[3] = a3;
    }
    {
      const short* vg = &Vbase[(size_t)vr * SEQT + kv0 + vc * 32];
      uint4 b0 = ((const uint4*)vg)[0];
      uint4 b1 = ((const uint4*)vg)[1];
      uint4 b2 = ((const uint4*)vg)[2];
      uint4 b3 = ((const uint4*)vg)[3];
      short* vd = &Vs[vr * VP + vc * 32];
      ((uint4*)vd)[0] = b0; ((uint4*)vd)[1] = b1;
      ((uint4*)vd)[2] = b2; ((uint4*)vd)[3] = b3;
    }
    __syncthreads();

#pragma unroll
    for (int h2 = 0; h2 < 2; h2++) {
      int kvh = kv0 + h2 * 64;
      if (kvh > qw) break;
      bool act1 = (kvh + 32 <= qw);
      bf16x8 ka0[4], ka1[4];
#pragma unroll
      for (int kk = 0; kk < 4; kk++)
        ka0[kk] = *(const bf16x8*)&Ks[(h2 * 64 + li) * AP + kk * 16 + hi * 8];
      if (act1) {
#pragma unroll
        for (int kk = 0; kk < 4; kk++)
          ka1[kk] = *(const bf16x8*)&Ks[(h2 * 64 + 32 + li) * AP + kk * 16 + hi * 8];
      }

      f32x16 st[2];
      {
        f32x16 a = {};
#pragma unroll
        for (int kk = 0; kk < 4; kk++)
          a = __builtin_amdgcn_mfma_f32_32x32x16_bf16(ka0[kk], qf[kk], a, 0, 0, 0);
        st[0] = a;
      }
      if (act1) {
        f32x16 a = {};
#pragma unroll
        for (int kk = 0; kk < 4; kk++)
          a = __builtin_amdgcn_mfma_f32_32x32x16_bf16(ka1[kk], qf[kk], a, 0, 0, 0);
        st[1] = a;
      }

      bool full0 = (kvh < qw);
      float mx = NEG_BIG;
      if (full0) {
#pragma unroll
        for (int r = 0; r < 16; r++) mx = fmaxf(mx, st[0][r]);
      } else {
        int thr = li - 4 * hi;
#pragma unroll
        for (int r = 0; r < 16; r++) {
          const int R = (r & 3) + 8 * (r >> 2);
          st[0][r] = (R <= thr) ? st[0][r] : NEG_BIG;
          mx = fmaxf(mx, st[0][r]);
        }
      }
      if (act1) {
        bool full1 = (kvh + 32 < qw);
        if (full1) {
#pragma unroll
          for (int r = 0; r < 16; r++) mx = fmaxf(mx, st[1][r]);
        } else {
          int thr = li - 4 * hi;
#pragma unroll
          for (int r = 0; r < 16; r++) {
            const int R = (r & 3) + 8 * (r >> 2);
            st[1][r] = (R <= thr) ? st[1][r] : NEG_BIG;
            mx = fmaxf(mx, st[1][r]);
          }
        }
      }
      mx = fmaxf(mx, __shfl_xor(mx, 32));
      float mn = fmaxf(m_s, mx);
      float c1 = SC * mn;
      float al = __builtin_amdgcn_exp2f(fminf(SC * m_s - c1, 0.f));
      m_s = mn;
      float sm = 0.f;
      unsigned pk[2][8];
#pragma unroll
      for (int r2 = 0; r2 < 8; r2++) {
        float pa = __builtin_amdgcn_exp2f(fminf(__builtin_fmaf(st[0][2 * r2],     SC, -c1), 0.f));
        float pb = __builtin_amdgcn_exp2f(fminf(__builtin_fmaf(st[0][2 * r2 + 1], SC, -c1), 0.f));
        sm += pa + pb;
        pk[0][r2] = pack_bf16(pa, pb);
      }
      if (act1) {
#pragma unroll
        for (int r2 = 0; r2 < 8; r2++) {
          float pa = __builtin_amdgcn_exp2f(fminf(__builtin_fmaf(st[1][2 * r2],     SC, -c1), 0.f));
          float pb = __builtin_amdgcn_exp2f(fminf(__builtin_fmaf(st[1][2 * r2 + 1], SC, -c1), 0.f));
          sm += pa + pb;
          pk[1][r2] = pack_bf16(pa, pb);
        }
      }
      sm += __shfl_xor(sm, 32);
      l_s = l_s * al + sm;
#pragma unroll
      for (int dt = 0; dt < 2; dt++)
#pragma unroll
        for (int r = 0; r < 16; r++) O[dt][r] *= al;

#pragma unroll
      for (int g = 0; g < 4; g++) {
        int t = g >> 1, k2 = g & 1;
        if (t == 1 && !act1) continue;
        unsigned own_a = hi ? pk[t][k2 * 4 + 2] : pk[t][k2 * 4 + 0];
        unsigned own_b = hi ? pk[t][k2 * 4 + 3] : pk[t][k2 * 4 + 1];
        unsigned snd_a = hi ? pk[t][k2 * 4 + 0] : pk[t][k2 * 4 + 2];
        unsigned snd_b = hi ? pk[t][k2 * 4 + 1] : pk[t][k2 * 4 + 3];
        unsigned rcv_a = (unsigned)__shfl_xor((int)snd_a, 32);
        unsigned rcv_b = (unsigned)__shfl_xor((int)snd_b, 32);
        union { unsigned u[4]; bf16x8 v; } pf;
        pf.u[0] = hi ? rcv_a : own_a;
        pf.u[1] = hi ? rcv_b : own_b;
        pf.u[2] = hi ? own_a : rcv_a;
        pf.u[3] = hi ? own_b : rcv_b;
        bf16x8 va0 = *(const bf16x8*)&Vs[li * VP + h2 * 64 + g * 16 + hi * 8];
        bf16x8 va1 = *(const bf16x8*)&Vs[(32 + li) * VP + h2 * 64 + g * 16 + hi * 8];
        O[0] = __builtin_amdgcn_mfma_f32_32x32x16_bf16(va0, pf.v, O[0], 0, 0, 0);
        O[1] = __builtin_amdgcn_mfma_f32_32x32x16_bf16(va1, pf.v, O[1], 0, 0, 0);
      }
    }
    __syncthreads();
  }

  int lq = w * 32 + li;
  short* op = &Opart[((size_t)cid * 128 + lq) * 64];
#pragma unroll
  for (int dt = 0; dt < 2; dt++) {
#pragma unroll
    for (int rg = 0; rg < 4; rg++) {
      uint2 u2;
      u2.x = pack_bf16(O[dt][rg * 4 + 0], O[dt][rg * 4 + 1]);
      u2.y = pack_bf16(O[dt][rg * 4 + 2], O[dt][rg * 4 + 3]);
      *(uint2*)(op + dt * 32 + rg * 8 + hi * 4) = u2;
    }
  }
  if (hi == 0) {
    float2 ml; ml.x = m_s; ml.y = l_s;
    Ml[(size_t)cid * 128 + lq] = ml;
  }
}

// ---------------- merge partials ----------------
__global__ __launch_bounds__(256) void merge_kernel(
    const short* __restrict__ Opart, const float2* __restrict__ Ml,
    short* __restrict__ Y) {
  int qt = blockIdx.x, bh = blockIdx.y;
  int n = (qt + 4) >> 2;
  int cbase = 0;
  for (int j = qt + 1; j < 32; j++) cbase += (j + 4) >> 2;
  int tid = threadIdx.x;
  int lq = tid >> 1, half = tid & 1;
  int b = bh / NHEAD, h = bh % NHEAD;
  int q = qt * 128 + lq;
  const float SC = 0.18033688011112042f;

  float m_i[8], l_i[8];
  float mstar = NEG_BIG;
#pragma unroll 4
  for (int i = 0; i < n; i++) {
    float2 ml = Ml[((size_t)bh * NCHUNK + cbase + i) * 128 + lq];
    m_i[i] = ml.x; l_i[i] = ml.y;
    mstar = fmaxf(mstar, ml.x);
  }
  float lstar = 0.f;
  float wgt[8];
#pragma unroll 4
  for (int i = 0; i < n; i++) {
    wgt[i] = __builtin_amdgcn_exp2f(fminf(SC * (m_i[i] - mstar), 0.f));
    lstar += l_i[i] * wgt[i];
  }

  float acc[32] = {};
#pragma unroll 4
  for (int i = 0; i < n; i++) {
    const short* op = &Opart[(((size_t)bh * NCHUNK + cbase + i) * 128 + lq) * 64 + half * 32];
    float wi = wgt[i];
#pragma unroll
    for (int v = 0; v < 4; v++) {
      uint4 u = ((const uint4*)op)[v];
      unsigned uu[4] = {u.x, u.y, u.z, u.w};
#pragma unroll
      for (int j = 0; j < 4; j++) {
        union { unsigned u; float f; } lo2, hi2;
        lo2.u = uu[j] << 16;
        hi2.u = uu[j] & 0xFFFF0000u;
        acc[v * 8 + j * 2]     = __builtin_fmaf(lo2.f, wi, acc[v * 8 + j * 2]);
        acc[v * 8 + j * 2 + 1] = __builtin_fmaf(hi2.f, wi, acc[v * 8 + j * 2 + 1]);
      }
    }
  }
  float rl = 1.f / lstar;
  short* yp = &Y[((size_t)b * SEQT + q) * EMB + h * 64 + half * 32];
#pragma unroll
  for (int v = 0; v < 4; v++) {
    uint2 u2;
    u2.x = pack_bf16(acc[v * 8 + 0] * rl, acc[v * 8 + 1] * rl);
    u2.y = pack_bf16(acc[v * 8 + 2] * rl, acc[v * 8 + 3] * rl);
    uint2 u3;
    u3.x = pack_bf16(acc[v * 8 + 4] * rl, acc[v * 8 + 5] * rl);
    u3.y = pack_bf16(acc[v * 8 + 6] * rl, acc[v * 8 + 7] * rl);
    *(uint2*)(yp + v * 8) = u2;
    *(uint2*)(yp + v * 8 + 4) = u3;
  }
}

extern "C" void kernel_launch(void* const* d_in, const int* in_sizes, int n_in,
                              void* d_out, int out_size, void* d_ws, size_t ws_size,
                              hipStream_t stream) {
  const float* x      = (const float*)d_in[0];   // [2,4096,768]
  const float* W_attn = (const float*)d_in[1];   // [768,2304]
  const float* b_attn = (const float*)d_in[2];   // [2304]
  const float* W_proj = (const float*)d_in[3];   // [768,768]
  const float* b_proj = (const float*)d_in[4];   // [768]
  float* out = (float*)d_out;                    // [2,4096,768] fp32

  char* ws = (char*)d_ws;
  short* x_bf  = (short*)(ws + 0);           // 8192x768 bf16
  short* Wt_a  = (short*)(ws + 12582912);    // 2304x768 bf16
  short* Wt_p  = (short*)(ws + 16121856);    // 768x768  bf16
  short* Qg    = (short*)(ws + 17301504);    // [2,12,4096,64]
  short* Kg    = (short*)(ws + 29884416);    // [2,12,4096,64]
  short* Vtg   = (short*)(ws + 42467328);    // [2,12,64,4096]
  short* Ybf   = (short*)(ws + 55050240);    // 8192x768 bf16
  short* Opart = (short*)(ws + 67633152);    // 3456 x 128 x 64 bf16 = 56,623,104 B
  float2* Ml   = (float2*)(ws + 124256256);  // 3456 x 128 float2 = 3,538,944 B
  // total 127,795,200 B

  prep_kernel<<<8448, 256, 0, stream>>>(x, x_bf, W_attn, Wt_a, W_proj, Wt_p);

  gemm_qkv_kernel<<<dim3(64, 18), 256, 0, stream>>>(x_bf, Wt_a, b_attn, 768,
                                                    Qg, Kg, Vtg);
  attn_kernel<<<dim3(NCHUNK, 24), 256, 0, stream>>>(Qg, Kg, Vtg, Opart, Ml);
  merge_kernel<<<dim3(32, 24), 256, 0, stream>>>(Opart, Ml, Ybf);
  gemm_proj_kernel<<<dim3(64, 12), 256, 0, stream>>>(Ybf, Wt_p, b_proj, out);
}